// Round 8
// baseline (83.476 us; speedup 1.0000x reference)
//
#include <hip/hip_runtime.h>

#define N_NODES 200000
#define NTILES  6250        // 32-node tiles, exact
#define NBLK    512         // 2 blocks/CU (65.5KB LDS each)
#define TPB     512         // 8 waves/block; 4096 waves total
#define NWAVES  4096
#define NREP    64

typedef __attribute__((ext_vector_type(8))) short short8;   // bf16x8 (4 VGPR)
typedef __attribute__((ext_vector_type(4))) float f32x4;
typedef __attribute__((ext_vector_type(4))) unsigned int u32x4;

__device__ __forceinline__ unsigned int pk2(float a, float b) {
  unsigned int d;   // lo16 = bf16(a), hi16 = bf16(b)
  asm("v_cvt_pk_bf16_f32 %0, %1, %2" : "=v"(d) : "v"(a), "v"(b));
  return d;
}
__device__ __forceinline__ short8 pk8(f32x4 lo, f32x4 hi) {
  u32x4 u = { pk2(lo[0], lo[1]), pk2(lo[2], lo[3]),
              pk2(hi[0], hi[1]), pk2(hi[2], hi[3]) };
  return __builtin_bit_cast(short8, u);
}
__device__ __forceinline__ f32x4 mfma16(short8 a, short8 b, f32x4 c) {
  return __builtin_amdgcn_mfma_f32_16x16x32_bf16(a, b, c, 0, 0, 0);
}

__global__ __launch_bounds__(TPB, 4) void gcn_main(
    const float* __restrict__ x,  const float* __restrict__ W1,
    const float* __restrict__ b1, const float* __restrict__ W2,
    const float* __restrict__ b2, float* __restrict__ sums)
{
  __shared__ char  wlds[65536];    // W1 @0, W2 @32768 (bf16, swizzled A-tiles)
  __shared__ float blds[256];      // b1[128] | b2[128]

  const int tid  = threadIdx.x;
  const int lane = tid & 63;
  const int wid  = tid >> 6;
  const int r = lane & 15;         // MFMA row/col-in-16
  const int g = lane >> 4;         // k-group 0..3

  // ---- stage W1,W2 (swizzled bf16 A-tiles) + biases into LDS ----
  if (tid < 128) { blds[tid] = b1[tid]; blds[128 + tid] = b2[tid]; }
  #pragma unroll
  for (int l = 0; l < 2; ++l) {
    const float* W = l ? W2 : W1;
    char* dst = wlds + l * 32768;
    #pragma unroll
    for (int i = 0; i < 4; ++i) {
      const int c = tid + i * 512;             // 16B-chunk id 0..2047
      const int f = c >> 4, s = c & 15;
      const f32x4* src = (const f32x4*)(W + f * 128 + s * 8);
      *(short8*)(dst + f * 256 + ((s ^ (f & 7)) << 4)) = pk8(src[0], src[1]);
    }
  }
  __syncthreads();   // only barrier; loop below is barrier-free

  // ---- contiguous per-wave tile range (bijective split of 6250/4096) ----
  const int wgid = (int)blockIdx.x * 8 + wid;
  const int rem  = NTILES % NWAVES;            // 2154 (q = 1)
  const int t0   = wgid + (wgid < rem ? wgid : rem);
  const int cnt  = 1 + (wgid < rem ? 1 : 0);

  const f32x4 zero4 = {0.f, 0.f, 0.f, 0.f};
  f32x4 sum8[8];
  #pragma unroll
  for (int ft = 0; ft < 8; ++ft) sum8[ft] = zero4;

  for (int i = 0; i < cnt; ++i) {
    const int t = t0 + i;
    const float* bx = x + (size_t)t * 4096;

    // ---- load + pack this tile's B-frags ----
    short8 xb[8];
    #pragma unroll
    for (int nt = 0; nt < 2; ++nt)
      #pragma unroll
      for (int ks = 0; ks < 4; ++ks) {
        const float* p = bx + (nt * 16 + r) * 128 + ks * 32 + g * 8;
        xb[nt * 4 + ks] = pk8(*(const f32x4*)(p), *(const f32x4*)(p + 4));
      }

    // ---- layer 1: A = W1 (LDS); 4 passes of 2 f-tiles; out -> hp regs ----
    unsigned int hp[8][2][2];   // [ft][nt][s]: pk2 of features g*4+2s,2s+1
    #pragma unroll
    for (int pass = 0; pass < 4; ++pass) {
      f32x4 acc[2][2];
      #pragma unroll
      for (int f2 = 0; f2 < 2; ++f2) { acc[f2][0] = zero4; acc[f2][1] = zero4; }
      #pragma unroll
      for (int ks = 0; ks < 4; ++ks)
        #pragma unroll
        for (int f2 = 0; f2 < 2; ++f2) {
          const int ft = pass * 2 + f2;
          short8 af = *(const short8*)(wlds + (ft * 16 + r) * 256 +
                                       (((ks * 4 + g) ^ (r & 7)) << 4));
          acc[f2][0] = mfma16(af, xb[ks],     acc[f2][0]);
          acc[f2][1] = mfma16(af, xb[4 + ks], acc[f2][1]);
        }
      #pragma unroll
      for (int f2 = 0; f2 < 2; ++f2) {
        const int ft = pass * 2 + f2;
        const f32x4 bf = *(const f32x4*)(blds + ft * 16 + g * 4);
        #pragma unroll
        for (int nt = 0; nt < 2; ++nt) {
          float v0 = fmaxf(acc[f2][nt][0] + bf[0], 0.f);
          float v1 = fmaxf(acc[f2][nt][1] + bf[1], 0.f);
          float v2 = fmaxf(acc[f2][nt][2] + bf[2], 0.f);
          float v3 = fmaxf(acc[f2][nt][3] + bf[3], 0.f);
          hp[ft][nt][0] = pk2(v0, v1);
          hp[ft][nt][1] = pk2(v2, v3);
        }
      }
    }

    // ---- in-register C-layout -> B-frag transpose (4-lane g-groups) ----
    // D0,D1 = permlane16_swap(permlane32_swap(P0,P1)); P0=hp[2ks],P1=hp[2ks+1]
    #pragma unroll
    for (int ks = 0; ks < 4; ++ks)
      #pragma unroll
      for (int nt = 0; nt < 2; ++nt)
        #pragma unroll
        for (int s = 0; s < 2; ++s) {
          asm("v_permlane32_swap_b32 %0, %1\n\t"
              "v_permlane16_swap_b32 %0, %1"
              : "+v"(hp[2 * ks][nt][s]), "+v"(hp[2 * ks + 1][nt][s]));
        }
    short8 hb[2][4];
    #pragma unroll
    for (int nt = 0; nt < 2; ++nt)
      #pragma unroll
      for (int ks = 0; ks < 4; ++ks) {
        u32x4 u = { hp[2 * ks][nt][0], hp[2 * ks][nt][1],
                    hp[2 * ks + 1][nt][0], hp[2 * ks + 1][nt][1] };
        hb[nt][ks] = __builtin_bit_cast(short8, u);
      }

    // ---- layer 2: A = W2 (LDS), B = hb regs; fused column-sum ----
    #pragma unroll
    for (int pass = 0; pass < 4; ++pass) {
      f32x4 acc[2][2];
      #pragma unroll
      for (int f2 = 0; f2 < 2; ++f2) { acc[f2][0] = zero4; acc[f2][1] = zero4; }
      #pragma unroll
      for (int ks = 0; ks < 4; ++ks)
        #pragma unroll
        for (int f2 = 0; f2 < 2; ++f2) {
          const int ft = pass * 2 + f2;
          short8 af = *(const short8*)(wlds + 32768 + (ft * 16 + r) * 256 +
                                       (((ks * 4 + g) ^ (r & 7)) << 4));
          acc[f2][0] = mfma16(af, hb[0][ks], acc[f2][0]);
          acc[f2][1] = mfma16(af, hb[1][ks], acc[f2][1]);
        }
      #pragma unroll
      for (int f2 = 0; f2 < 2; ++f2) {
        const int ft = pass * 2 + f2;
        const f32x4 bf = *(const f32x4*)(blds + 128 + ft * 16 + g * 4);
        #pragma unroll
        for (int nt = 0; nt < 2; ++nt)
          #pragma unroll
          for (int qq = 0; qq < 4; ++qq)
            sum8[ft][qq] += fmaxf(acc[f2][nt][qq] + bf[qq], 0.f);
      }
    }
  }

  // ---- reduce over 16 node-lanes; g-lanes hold disjoint features ----
  #pragma unroll
  for (int ft = 0; ft < 8; ++ft)
    #pragma unroll
    for (int qq = 0; qq < 4; ++qq) {
      float v = sum8[ft][qq];
      v += __shfl_xor(v, 1, 64);
      v += __shfl_xor(v, 2, 64);
      v += __shfl_xor(v, 4, 64);
      v += __shfl_xor(v, 8, 64);
      sum8[ft][qq] = v;
    }
  if (r == 0) {
    const int rep = wgid & (NREP - 1);
    #pragma unroll
    for (int ft = 0; ft < 8; ++ft)
      #pragma unroll
      for (int qq = 0; qq < 4; ++qq)
        unsafeAtomicAdd(&sums[rep * 128 + ft * 16 + g * 4 + qq], sum8[ft][qq]);
  }
}

// mean -> W3 -> classifier -> log_softmax, fp32, trivial cost
__global__ void gcn_tail(const float* __restrict__ sums,
                         const float* __restrict__ W3, const float* __restrict__ b3,
                         const float* __restrict__ Wl, const float* __restrict__ bl,
                         float* __restrict__ out)
{
  __shared__ float h3[128];
  __shared__ float lg[16];
  int t = threadIdx.x;   // 128 threads
  float m = 0.f;
  for (int rp = 0; rp < NREP; ++rp) m += sums[rp * 128 + t];
  h3[t] = m * (1.0f / (float)N_NODES);
  __syncthreads();
  float accv = 0.f;
  for (int k = 0; k < 128; ++k) accv += h3[k] * W3[t * 128 + k];
  float h3o = b3[t] + accv;
  __syncthreads();
  h3[t] = h3o;
  __syncthreads();
  if (t < 10) {
    float a = bl[t];
    for (int j = 0; j < 128; ++j) a += h3[j] * Wl[t * 128 + j];
    lg[t] = a;
  }
  __syncthreads();
  if (t == 0) {
    float mx = lg[0];
    for (int c = 1; c < 10; ++c) mx = fmaxf(mx, lg[c]);
    float s = 0.f;
    for (int c = 0; c < 10; ++c) s += expf(lg[c] - mx);
    float lse = mx + logf(s);
    for (int c = 0; c < 10; ++c) out[c] = lg[c] - lse;
  }
}

extern "C" void kernel_launch(void* const* d_in, const int* in_sizes, int n_in,
                              void* d_out, int out_size, void* d_ws, size_t ws_size,
                              hipStream_t stream) {
  const float* x  = (const float*)d_in[0];
  // d_in[1] = edge_index (int64) — unused: ChebConv K=1 has no propagation
  const float* W1 = (const float*)d_in[2];
  const float* b1 = (const float*)d_in[3];
  const float* W2 = (const float*)d_in[4];
  const float* b2 = (const float*)d_in[5];
  const float* W3 = (const float*)d_in[6];
  const float* b3 = (const float*)d_in[7];
  const float* Wl = (const float*)d_in[8];
  const float* bl = (const float*)d_in[9];
  float* sums = (float*)d_ws;            // NREP x 128 floats
  float* out  = (float*)d_out;

  (void)hipMemsetAsync(sums, 0, NREP * 128 * sizeof(float), stream);
  gcn_main<<<NBLK, TPB, 0, stream>>>(x, W1, b1, W2, b2, sums);
  gcn_tail<<<1, 128, 0, stream>>>(sums, W3, b3, Wl, bl, out);
}

// Round 9
// 52.514 us; speedup vs baseline: 1.5896x; 1.5896x over previous
//
#include <hip/hip_runtime.h>

#define N_NODES 200000
#define NTILES  6250        // 32-node tiles, exact
#define NBLK    256         // 1 block/CU
#define TPB     512         // 8 waves; barrier-free after W-stage
#define NWAVES  2048
#define NREP    64
#define LDS_BYTES 132096    // 64KB W + 1KB bias + 8 x 8KB per-wave slab

typedef __attribute__((ext_vector_type(8))) short short8;   // bf16x8 (4 VGPR)
typedef __attribute__((ext_vector_type(4))) float f32x4;
typedef __attribute__((ext_vector_type(4))) unsigned int u32x4;

__device__ __forceinline__ unsigned int pk2(float a, float b) {
  unsigned int d;   // lo16 = bf16(a), hi16 = bf16(b)
  asm("v_cvt_pk_bf16_f32 %0, %1, %2" : "=v"(d) : "v"(a), "v"(b));
  return d;
}
__device__ __forceinline__ short8 pk8(f32x4 lo, f32x4 hi) {
  u32x4 u = { pk2(lo[0], lo[1]), pk2(lo[2], lo[3]),
              pk2(hi[0], hi[1]), pk2(hi[2], hi[3]) };
  return __builtin_bit_cast(short8, u);
}
__device__ __forceinline__ f32x4 mfma16(short8 a, short8 b, f32x4 c) {
  return __builtin_amdgcn_mfma_f32_16x16x32_bf16(a, b, c, 0, 0, 0);
}

__global__ __launch_bounds__(TPB, 2) void gcn_main(
    const float* __restrict__ x,  const float* __restrict__ W1,
    const float* __restrict__ b1, const float* __restrict__ W2,
    const float* __restrict__ b2, float* __restrict__ sums)
{
  extern __shared__ char lds[];
  char*  const wlds = lds;                     // W1 @0, W2 @32768 (bf16 swz)
  float* const blds = (float*)(lds + 65536);   // b1[128] | b2[128]
  const int tid  = threadIdx.x;
  const int lane = tid & 63;
  const int wid  = tid >> 6;
  char* const slab = lds + 66560 + wid * 8192; // per-wave: x-tile bf16, then h1
  const int r = lane & 15;                     // MFMA row/col-in-16
  const int g = lane >> 4;                     // k-group 0..3

  // ---- stage W1,W2 (swizzled bf16 A-tiles) + biases into LDS ----
  if (tid < 128) { blds[tid] = b1[tid]; blds[128 + tid] = b2[tid]; }
  #pragma unroll
  for (int l = 0; l < 2; ++l) {
    const float* W = l ? W2 : W1;
    char* dst = wlds + l * 32768;
    #pragma unroll
    for (int i = 0; i < 4; ++i) {
      const int c = tid + i * 512;             // 16B-chunk id 0..2047
      const int f = c >> 4, s = c & 15;
      const f32x4* src = (const f32x4*)(W + f * 128 + s * 8);
      *(short8*)(dst + f * 256 + ((s ^ (f & 7)) << 4)) = pk8(src[0], src[1]);
    }
  }
  __syncthreads();   // only barrier; loop below is barrier-free

  // ---- contiguous per-wave tile range (bijective split of 6250/2048) ----
  const int wgid = (int)blockIdx.x * 8 + wid;
  const int q = NTILES / NWAVES, rem = NTILES % NWAVES;   // 3, 106
  const int t0  = wgid * q + (wgid < rem ? wgid : rem);
  const int cnt = q + (wgid < rem ? 1 : 0);

  const f32x4 zero4 = {0.f, 0.f, 0.f, 0.f};
  f32x4 sum8[8];
  #pragma unroll
  for (int ft = 0; ft < 8; ++ft) sum8[ft] = zero4;

  for (int i = 0; i < cnt; ++i) {
    const int t = t0 + i;
    const float* bx = x + (size_t)t * 4096;

    // ---- a) COALESCED x load (lane-linear, 2KB contiguous per step),
    //      b) pack bf16, write linear-swizzled [n][k] image into slab ----
    #pragma unroll
    for (int j = 0; j < 8; ++j) {
      const float* p = bx + j * 512 + lane * 8;   // 32B contiguous per lane
      f32x4 lo = *(const f32x4*)p;
      f32x4 hi = *(const f32x4*)(p + 4);
      const int n = j * 4 + (lane >> 4);          // node of this 16B unit
      const int u = lane & 15;                    // 16B unit within node row
      *(short8*)(slab + n * 256 + ((u ^ (n & 7)) << 4)) = pk8(lo, hi);
    }

    // ---- c) lift x B-frags to registers (slab then dead -> reused as h1) ----
    short8 xb[8];
    #pragma unroll
    for (int nt = 0; nt < 2; ++nt)
      #pragma unroll
      for (int ks = 0; ks < 4; ++ks) {
        const int n = nt * 16 + r;
        xb[nt * 4 + ks] = *(const short8*)(
            slab + n * 256 + (((ks * 4 + g) ^ (n & 7)) << 4));
      }

    // ---- d) layer 1: A = W1 (LDS); 4 passes of 2 f-tiles; out -> slab(h1) --
    #pragma unroll
    for (int pass = 0; pass < 4; ++pass) {
      f32x4 acc[2][2];
      #pragma unroll
      for (int f2 = 0; f2 < 2; ++f2) { acc[f2][0] = zero4; acc[f2][1] = zero4; }
      #pragma unroll
      for (int ks = 0; ks < 4; ++ks)
        #pragma unroll
        for (int f2 = 0; f2 < 2; ++f2) {
          const int ft = pass * 2 + f2;
          short8 af = *(const short8*)(wlds + (ft * 16 + r) * 256 +
                                       (((ks * 4 + g) ^ (r & 7)) << 4));
          acc[f2][0] = mfma16(af, xb[ks],     acc[f2][0]);
          acc[f2][1] = mfma16(af, xb[4 + ks], acc[f2][1]);
        }
      #pragma unroll
      for (int f2 = 0; f2 < 2; ++f2) {
        const int ft = pass * 2 + f2;
        const f32x4 bf = *(const f32x4*)(blds + ft * 16 + g * 4);
        const int s = ft * 2 + (g >> 1);
        const int half = (g & 1) * 8;
        #pragma unroll
        for (int nt = 0; nt < 2; ++nt) {
          const int n = nt * 16 + r;
          float v0 = fmaxf(acc[f2][nt][0] + bf[0], 0.f);
          float v1 = fmaxf(acc[f2][nt][1] + bf[1], 0.f);
          float v2 = fmaxf(acc[f2][nt][2] + bf[2], 0.f);
          float v3 = fmaxf(acc[f2][nt][3] + bf[3], 0.f);
          unsigned long long w =
              (unsigned long long)pk2(v0, v1) |
              ((unsigned long long)pk2(v2, v3) << 32);
          *(unsigned long long*)(slab + n * 256 + ((s ^ (n & 7)) << 4) + half) = w;
        }
      }
    }

    // ---- e) lift h1 B-frags to registers (read once, reuse in 4 passes) ----
    short8 hb[2][4];
    #pragma unroll
    for (int nt = 0; nt < 2; ++nt)
      #pragma unroll
      for (int ks = 0; ks < 4; ++ks) {
        const int n = nt * 16 + r;
        hb[nt][ks] = *(const short8*)(
            slab + n * 256 + (((ks * 4 + g) ^ (n & 7)) << 4));
      }

    // ---- f) layer 2: A = W2 (LDS), B = hb regs; fused column-sum ----
    #pragma unroll
    for (int pass = 0; pass < 4; ++pass) {
      f32x4 acc[2][2];
      #pragma unroll
      for (int f2 = 0; f2 < 2; ++f2) { acc[f2][0] = zero4; acc[f2][1] = zero4; }
      #pragma unroll
      for (int ks = 0; ks < 4; ++ks)
        #pragma unroll
        for (int f2 = 0; f2 < 2; ++f2) {
          const int ft = pass * 2 + f2;
          short8 af = *(const short8*)(wlds + 32768 + (ft * 16 + r) * 256 +
                                       (((ks * 4 + g) ^ (r & 7)) << 4));
          acc[f2][0] = mfma16(af, hb[0][ks], acc[f2][0]);
          acc[f2][1] = mfma16(af, hb[1][ks], acc[f2][1]);
        }
      #pragma unroll
      for (int f2 = 0; f2 < 2; ++f2) {
        const int ft = pass * 2 + f2;
        const f32x4 bf = *(const f32x4*)(blds + 128 + ft * 16 + g * 4);
        #pragma unroll
        for (int nt = 0; nt < 2; ++nt)
          #pragma unroll
          for (int qq = 0; qq < 4; ++qq)
            sum8[ft][qq] += fmaxf(acc[f2][nt][qq] + bf[qq], 0.f);
      }
    }
  }

  // ---- reduce over 16 node-lanes; g-lanes hold disjoint features ----
  #pragma unroll
  for (int ft = 0; ft < 8; ++ft)
    #pragma unroll
    for (int qq = 0; qq < 4; ++qq) {
      float v = sum8[ft][qq];
      v += __shfl_xor(v, 1, 64);
      v += __shfl_xor(v, 2, 64);
      v += __shfl_xor(v, 4, 64);
      v += __shfl_xor(v, 8, 64);
      sum8[ft][qq] = v;
    }
  if (r == 0) {
    const int rep = wgid & (NREP - 1);
    #pragma unroll
    for (int ft = 0; ft < 8; ++ft)
      #pragma unroll
      for (int qq = 0; qq < 4; ++qq)
        unsafeAtomicAdd(&sums[rep * 128 + ft * 16 + g * 4 + qq], sum8[ft][qq]);
  }
}

// mean -> W3 -> classifier -> log_softmax, fp32, trivial cost
__global__ void gcn_tail(const float* __restrict__ sums,
                         const float* __restrict__ W3, const float* __restrict__ b3,
                         const float* __restrict__ Wl, const float* __restrict__ bl,
                         float* __restrict__ out)
{
  __shared__ float h3[128];
  __shared__ float lg[16];
  int t = threadIdx.x;   // 128 threads
  float m = 0.f;
  for (int rp = 0; rp < NREP; ++rp) m += sums[rp * 128 + t];
  h3[t] = m * (1.0f / (float)N_NODES);
  __syncthreads();
  float accv = 0.f;
  for (int k = 0; k < 128; ++k) accv += h3[k] * W3[t * 128 + k];
  float h3o = b3[t] + accv;
  __syncthreads();
  h3[t] = h3o;
  __syncthreads();
  if (t < 10) {
    float a = bl[t];
    for (int j = 0; j < 128; ++j) a += h3[j] * Wl[t * 128 + j];
    lg[t] = a;
  }
  __syncthreads();
  if (t == 0) {
    float mx = lg[0];
    for (int c = 1; c < 10; ++c) mx = fmaxf(mx, lg[c]);
    float s = 0.f;
    for (int c = 0; c < 10; ++c) s += expf(lg[c] - mx);
    float lse = mx + logf(s);
    for (int c = 0; c < 10; ++c) out[c] = lg[c] - lse;
  }
}

extern "C" void kernel_launch(void* const* d_in, const int* in_sizes, int n_in,
                              void* d_out, int out_size, void* d_ws, size_t ws_size,
                              hipStream_t stream) {
  const float* x  = (const float*)d_in[0];
  // d_in[1] = edge_index (int64) — unused: ChebConv K=1 has no propagation
  const float* W1 = (const float*)d_in[2];
  const float* b1 = (const float*)d_in[3];
  const float* W2 = (const float*)d_in[4];
  const float* b2 = (const float*)d_in[5];
  const float* W3 = (const float*)d_in[6];
  const float* b3 = (const float*)d_in[7];
  const float* Wl = (const float*)d_in[8];
  const float* bl = (const float*)d_in[9];
  float* sums = (float*)d_ws;            // NREP x 128 floats
  float* out  = (float*)d_out;

  (void)hipFuncSetAttribute((const void*)gcn_main,
                            hipFuncAttributeMaxDynamicSharedMemorySize,
                            LDS_BYTES);
  (void)hipMemsetAsync(sums, 0, NREP * 128 * sizeof(float), stream);
  gcn_main<<<NBLK, TPB, LDS_BYTES, stream>>>(x, W1, b1, W2, b2, sums);
  gcn_tail<<<1, 128, 0, stream>>>(sums, W3, b3, Wl, bl, out);
}

// Round 10
// 45.935 us; speedup vs baseline: 1.8173x; 1.1432x over previous
//
#include <hip/hip_runtime.h>

#define N_NODES 200000
#define NTILES  3125        // 64-node tiles, exact
#define NBLK    768         // 3 blocks/CU (48KB LDS each), 12 waves/CU
#define TPB     256         // 4 waves x 32 features
#define NREP    64

typedef __attribute__((ext_vector_type(8))) short short8;   // bf16x8 (4 VGPR)
typedef __attribute__((ext_vector_type(4))) float f32x4;
typedef __attribute__((ext_vector_type(4))) unsigned int u32x4;

__device__ __forceinline__ unsigned int pk2(float a, float b) {
  unsigned int d;   // lo16 = bf16(a), hi16 = bf16(b)
  asm("v_cvt_pk_bf16_f32 %0, %1, %2" : "=v"(d) : "v"(a), "v"(b));
  return d;
}
__device__ __forceinline__ short8 pk8(f32x4 lo, f32x4 hi) {
  u32x4 u = { pk2(lo[0], lo[1]), pk2(lo[2], lo[3]),
              pk2(hi[0], hi[1]), pk2(hi[2], hi[3]) };
  return __builtin_bit_cast(short8, u);
}
__device__ __forceinline__ f32x4 mfma16(short8 a, short8 b, f32x4 c) {
  return __builtin_amdgcn_mfma_f32_16x16x32_bf16(a, b, c, 0, 0, 0);
}
__device__ __forceinline__ void glds16(const char* g, char* l) {
  __builtin_amdgcn_global_load_lds(
      (const __attribute__((address_space(1))) void*)g,
      (__attribute__((address_space(3))) void*)l, 16, 0, 0);
}

__global__ __launch_bounds__(TPB, 3) void gcn_main(
    const float* __restrict__ x,  const float* __restrict__ W1,
    const float* __restrict__ b1, const float* __restrict__ W2,
    const float* __restrict__ b2, float* __restrict__ sums)
{
  // Block-shared: x tile fp32 (src-swizzled via glds), h1 bf16 (swizzled).
  __shared__ char xbuf[32768];   // [64 n][512 B fp32]; LDS[n][u] = x[n][u^(n&7)]
  __shared__ char h1[16384];     // [64 n][256 B bf16], 16B-unit swizzle ^(n&7)

  const int tid  = threadIdx.x;
  const int lane = tid & 63;
  const int wid  = tid >> 6;       // wave owns features wid*32 .. +31
  const int r = lane & 15;
  const int g = lane >> 4;         // 0..3
  const int wf0 = wid * 32;

  // ---- per-wave W slices as A-operand fragments in registers ----
  short8 w1f[2][4], w2f[2][4];
  #pragma unroll
  for (int f2 = 0; f2 < 2; ++f2) {
    const int f = wf0 + f2 * 16 + r;
    #pragma unroll
    for (int ks = 0; ks < 4; ++ks) {
      const f32x4* p1 = (const f32x4*)(W1 + f * 128 + ks * 32 + g * 8);
      const f32x4* p2 = (const f32x4*)(W2 + f * 128 + ks * 32 + g * 8);
      w1f[f2][ks] = pk8(p1[0], p1[1]);
      w2f[f2][ks] = pk8(p2[0], p2[1]);
    }
  }
  f32x4 bias1[2], bias2[2];
  #pragma unroll
  for (int f2 = 0; f2 < 2; ++f2) {
    bias1[f2] = *(const f32x4*)(b1 + wf0 + f2 * 16 + g * 4);
    bias2[f2] = *(const f32x4*)(b2 + wf0 + f2 * 16 + g * 4);
  }

  // ---- contiguous per-block tile range (3125 = 768*4 + 53) ----
  const int bid = (int)blockIdx.x;
  const int t0  = bid * 4 + (bid < 53 ? bid : 53);
  const int cnt = 4 + (bid < 53 ? 1 : 0);

  // ---- async x staging: 2048 16B chunks, 8 per thread, pre-swizzled src ----
#define STAGE(tile)                                                            \
  {                                                                            \
    const char* bx = (const char*)(x + (size_t)(tile) * 8192);                 \
    _Pragma("unroll")                                                          \
    for (int ii = 0; ii < 8; ++ii) {                                           \
      const int c = tid + ii * 256;                                            \
      const int n = c >> 5, u = c & 31;                                        \
      glds16(bx + n * 512 + ((u ^ (n & 7)) << 4), xbuf + c * 16);              \
    }                                                                          \
  }

  STAGE(t0);

  const f32x4 zero4 = {0.f, 0.f, 0.f, 0.f};
  f32x4 sum8[2] = {zero4, zero4};

  for (int i = 0; i < cnt; ++i) {
    __syncthreads();               // own vmcnt drained by compiler -> x ready

    // ---- layer 1: A = W1 regs, B = x (shared LDS, fp32 -> pk8 at use) ----
    f32x4 acc[2][4];
    #pragma unroll
    for (int f2 = 0; f2 < 2; ++f2)
      #pragma unroll
      for (int nt = 0; nt < 4; ++nt) acc[f2][nt] = zero4;
    #pragma unroll
    for (int nt = 0; nt < 4; ++nt) {
      const int n = nt * 16 + r, s = n & 7;
      const char* base = xbuf + n * 512;
      #pragma unroll
      for (int ks = 0; ks < 4; ++ks) {
        const int u0 = ks * 8 + g * 2;
        f32x4 lo = *(const f32x4*)(base + ((u0 ^ s) << 4));
        f32x4 hi = *(const f32x4*)(base + (((u0 + 1) ^ s) << 4));
        short8 bfr = pk8(lo, hi);
        acc[0][nt] = mfma16(w1f[0][ks], bfr, acc[0][nt]);
        acc[1][nt] = mfma16(w1f[1][ks], bfr, acc[1][nt]);
      }
    }

    // ---- epilogue 1: bias+relu, 4 features packed -> one b64 per (f2,nt) ----
    #pragma unroll
    for (int f2 = 0; f2 < 2; ++f2) {
      const int unit = wid * 4 + f2 * 2 + (g >> 1);
      const int half = (g & 1) * 8;
      #pragma unroll
      for (int nt = 0; nt < 4; ++nt) {
        const int n = nt * 16 + r;
        float v0 = fmaxf(acc[f2][nt][0] + bias1[f2][0], 0.f);
        float v1 = fmaxf(acc[f2][nt][1] + bias1[f2][1], 0.f);
        float v2 = fmaxf(acc[f2][nt][2] + bias1[f2][2], 0.f);
        float v3 = fmaxf(acc[f2][nt][3] + bias1[f2][3], 0.f);
        unsigned long long w =
            (unsigned long long)pk2(v0, v1) |
            ((unsigned long long)pk2(v2, v3) << 32);
        *(unsigned long long*)(h1 + n * 256 + ((unit ^ (n & 7)) << 4) + half) = w;
      }
    }
    __syncthreads();               // h1 ready; xbuf fully consumed

    if (i + 1 < cnt) STAGE(t0 + i + 1);   // DMA flies under layer-2 compute

    // ---- layer 2: A = W2 regs, B = h1 (shared LDS bf16); fused col-sum ----
    #pragma unroll
    for (int f2 = 0; f2 < 2; ++f2)
      #pragma unroll
      for (int nt = 0; nt < 4; ++nt) acc[f2][nt] = zero4;
    #pragma unroll
    for (int nt = 0; nt < 4; ++nt) {
      const int n = nt * 16 + r, s = n & 7;
      #pragma unroll
      for (int ks = 0; ks < 4; ++ks) {
        short8 hbr = *(const short8*)(h1 + n * 256 + (((ks * 4 + g) ^ s) << 4));
        acc[0][nt] = mfma16(w2f[0][ks], hbr, acc[0][nt]);
        acc[1][nt] = mfma16(w2f[1][ks], hbr, acc[1][nt]);
      }
    }
    #pragma unroll
    for (int f2 = 0; f2 < 2; ++f2)
      #pragma unroll
      for (int nt = 0; nt < 4; ++nt)
        #pragma unroll
        for (int qq = 0; qq < 4; ++qq)
          sum8[f2][qq] += fmaxf(acc[f2][nt][qq] + bias2[f2][qq], 0.f);
  }

  // ---- reduce over the 16 node-lanes (same g => same features) ----
  #pragma unroll
  for (int f2 = 0; f2 < 2; ++f2)
    #pragma unroll
    for (int qq = 0; qq < 4; ++qq) {
      float v = sum8[f2][qq];
      v += __shfl_xor(v, 1, 64);
      v += __shfl_xor(v, 2, 64);
      v += __shfl_xor(v, 4, 64);
      v += __shfl_xor(v, 8, 64);
      sum8[f2][qq] = v;
    }
  if (r == 0) {
    const int rep = bid & (NREP - 1);
    #pragma unroll
    for (int f2 = 0; f2 < 2; ++f2)
      #pragma unroll
      for (int qq = 0; qq < 4; ++qq)
        unsafeAtomicAdd(&sums[rep * 128 + wf0 + f2 * 16 + g * 4 + qq],
                        sum8[f2][qq]);
  }
#undef STAGE
}

// mean -> W3 -> classifier -> log_softmax, fp32, trivial cost
__global__ void gcn_tail(const float* __restrict__ sums,
                         const float* __restrict__ W3, const float* __restrict__ b3,
                         const float* __restrict__ Wl, const float* __restrict__ bl,
                         float* __restrict__ out)
{
  __shared__ float h3[128];
  __shared__ float lg[16];
  int t = threadIdx.x;   // 128 threads
  float m = 0.f;
  for (int rp = 0; rp < NREP; ++rp) m += sums[rp * 128 + t];
  h3[t] = m * (1.0f / (float)N_NODES);
  __syncthreads();
  float accv = 0.f;
  for (int k = 0; k < 128; ++k) accv += h3[k] * W3[t * 128 + k];
  float h3o = b3[t] + accv;
  __syncthreads();
  h3[t] = h3o;
  __syncthreads();
  if (t < 10) {
    float a = bl[t];
    for (int j = 0; j < 128; ++j) a += h3[j] * Wl[t * 128 + j];
    lg[t] = a;
  }
  __syncthreads();
  if (t == 0) {
    float mx = lg[0];
    for (int c = 1; c < 10; ++c) mx = fmaxf(mx, lg[c]);
    float s = 0.f;
    for (int c = 0; c < 10; ++c) s += expf(lg[c] - mx);
    float lse = mx + logf(s);
    for (int c = 0; c < 10; ++c) out[c] = lg[c] - lse;
  }
}

extern "C" void kernel_launch(void* const* d_in, const int* in_sizes, int n_in,
                              void* d_out, int out_size, void* d_ws, size_t ws_size,
                              hipStream_t stream) {
  const float* x  = (const float*)d_in[0];
  // d_in[1] = edge_index (int64) — unused: ChebConv K=1 has no propagation
  const float* W1 = (const float*)d_in[2];
  const float* b1 = (const float*)d_in[3];
  const float* W2 = (const float*)d_in[4];
  const float* b2 = (const float*)d_in[5];
  const float* W3 = (const float*)d_in[6];
  const float* b3 = (const float*)d_in[7];
  const float* Wl = (const float*)d_in[8];
  const float* bl = (const float*)d_in[9];
  float* sums = (float*)d_ws;            // NREP x 128 floats
  float* out  = (float*)d_out;

  (void)hipMemsetAsync(sums, 0, NREP * 128 * sizeof(float), stream);
  gcn_main<<<NBLK, TPB, 0, stream>>>(x, W1, b1, W2, b2, sums);
  gcn_tail<<<1, 128, 0, stream>>>(sums, W3, b3, Wl, bl, out);
}